// Round 2
// baseline (255.021 us; speedup 1.0000x reference)
//
#include <hip/hip_runtime.h>
#include <cstdint>

// Bayesian LSTM: B=4096, T=200, IN=79, H=10 (gates G=40)
// ws layout (floats): [0,3160) Wih_hat, [3160,3560) Whh_hat, [3560,3600) bias_hat,
//                     [4096, 4096 + bc*T*G + 64) xg chunk buffer (b-chunked)
#define Bsz 4096
#define Tlen 200
#define INs 79
#define Hs 10
#define Gs 40

__global__ void prep_kernel(const float* __restrict__ wih_mu, const float* __restrict__ wih_rho, const float* __restrict__ wih_eps,
                            const float* __restrict__ whh_mu, const float* __restrict__ whh_rho, const float* __restrict__ whh_eps,
                            const float* __restrict__ b_mu,   const float* __restrict__ b_rho,   const float* __restrict__ b_eps,
                            float* __restrict__ w) {
    int i = blockIdx.x * 256 + threadIdx.x;
    if (i >= 3600) return;
    const float *mu, *rho, *eps; int k;
    if (i < 3160)      { mu = wih_mu; rho = wih_rho; eps = wih_eps; k = i; }
    else if (i < 3560) { mu = whh_mu; rho = whh_rho; eps = whh_eps; k = i - 3160; }
    else               { mu = b_mu;   rho = b_rho;   eps = b_eps;   k = i - 3560; }
    float r = rho[k];
    float sp = (r > 20.0f) ? r : log1pf(expf(r));   // softplus, stable
    w[i] = fmaf(sp, eps[k], mu[k]);
}

// Projection: xg[t][b_local][j'] = (x[b,t,:] @ Wih)[perm(j')] + bias[perm(j')]
// perm(j) = (j&3)*10 + (j>>2)  (quad-interleaved gate layout for the recurrence)
// One wave handles 64 contiguous (b,t) rows: coalesced float4 stage into
// wave-private LDS; stride-79 LDS reads are bank-conflict-free (gcd(15,32)=1).
// Wih rows are wave-uniform -> compiler emits s_load; FMA uses SGPR operand.
__global__ __launch_bounds__(128) void proj_kernel(
    const float* __restrict__ x, const float* __restrict__ w,
    float* __restrict__ xg, int b0, int bc) {
    __shared__ float lx[2][64 * INs];          // 2 waves * 20224 B
    const int wave = threadIdx.x >> 6, lane = threadIdx.x & 63;
    const long nrows = (long)bc * Tlen;
    const long row0 = ((long)blockIdx.x * 2 + wave) * 64;
    if (row0 >= nrows) return;                 // wave-private LDS: safe to exit
    float* myl = lx[wave];
    // 64 rows * 79 floats = 5056 floats = 1264 float4, 16B-aligned (64*79*4 % 16 == 0)
    const float4* s4 = (const float4*)(x + ((long)b0 * Tlen + row0) * INs);
    float4* l4 = (float4*)myl;
#pragma unroll
    for (int it = 0; it < 19; ++it) l4[it * 64 + lane] = s4[it * 64 + lane];
    if (lane < 48) l4[19 * 64 + lane] = s4[19 * 64 + lane];

    float acc[Gs];
#pragma unroll
    for (int c = 0; c < Gs; ++c) acc[c] = w[3560 + c];   // bias init (uniform s_load)
    const float* xr = myl + lane * INs;
    for (int i = 0; i < INs; ++i) {
        float xv = xr[i];
        const float* wr = w + i * Gs;
#pragma unroll
        for (int c = 0; c < Gs; ++c) acc[c] = fmaf(xv, wr[c], acc[c]);
    }
    long rg = row0 + lane;
    int bl = (int)(rg / Tlen), t = (int)(rg % Tlen);
    float4* dst = (float4*)(xg + ((long)t * bc + bl) * Gs);
#pragma unroll
    for (int q = 0; q < 10; ++q) {
        // stored[4q+ty] = acc[ty*10+q]  (== acc[perm(4q+ty)])
        float4 v = make_float4(acc[q], acc[10 + q], acc[20 + q], acc[30 + q]);
        dst[q] = v;
    }
}

// Recurrence: one wave per batch row. Lane j<40: unit u=j>>2, type ty=j&3
// (ty: 0=i, 1=f, 2=g, 3=o). h broadcast as wave-uniform scalars via readlane;
// i/f/g/o combine via DPP quad_perm (xor1=0xB1, xor2=0x4E, xor3=0x1B).
__global__ __launch_bounds__(256) void rec_kernel(
    const float* __restrict__ xg, const float* __restrict__ w,
    const float* __restrict__ lin_w, const float* __restrict__ lin_b,
    float* __restrict__ out, int b0, int bc) {
    const int lane = threadIdx.x & 63;
    const int bl = blockIdx.x * 4 + (threadIdx.x >> 6);
    if (bl >= bc) return;
    const int j = lane;
    int pj = (j & 3) * 10 + (j >> 2); pj = pj > 39 ? 39 : pj;  // clamp for lanes 40..63
    float wc[Hs];
#pragma unroll
    for (int k = 0; k < Hs; ++k) wc[k] = w[3160 + k * Gs + pj];  // Whh column (permuted)
    const int ty = j & 3;
    const float sA = (ty == 2) ? -2.0f : -1.0f;   // exp(-x) vs exp(-2x)
    const float sM = (ty == 2) ?  2.0f :  1.0f;   // tanh = 2*sigmoid(2x)-1
    const float sC = (ty == 2) ? -1.0f :  0.0f;
    float hs[Hs];
#pragma unroll
    for (int k = 0; k < Hs; ++k) hs[k] = 0.0f;
    float c = 0.0f;
    const long strideT = (long)bc * Gs;
    const float* gp = xg + (long)bl * Gs + j;
    float gcur = *gp;                              // t=0 gates (prefetched)
    for (int t = 0; t < Tlen; ++t) {
        const float* gpn = gp + ((t < Tlen - 1) ? strideT : 0);
        float gn = *gpn;                           // prefetch next step
        float acc = gcur;
#pragma unroll
        for (int k = 0; k < Hs; ++k) acc = fmaf(hs[k], wc[k], acc);  // h (SGPR) * Whh
        float e  = __expf(acc * sA);
        float sg = __builtin_amdgcn_rcpf(1.0f + e);
        float act = fmaf(sg, sM, sC);              // sigmoid (i,f,o) / tanh (g)
        int ai = __float_as_int(act);
        float a1 = __int_as_float(__builtin_amdgcn_mov_dpp(ai, 0xB1, 0xF, 0xF, true)); // quad xor1
        float a2 = __int_as_float(__builtin_amdgcn_mov_dpp(ai, 0x4E, 0xF, 0xF, true)); // quad xor2
        float a3 = __int_as_float(__builtin_amdgcn_mov_dpp(ai, 0x1B, 0xF, 0xF, true)); // quad xor3
        // valid in ty==0 lanes: act=i, a1=f, a2=g, a3=o
        c = fmaf(a1, c, act * a2);                 // c = f*c + i*g
        float e2 = __expf(-2.0f * c);
        float th = fmaf(2.0f, __builtin_amdgcn_rcpf(1.0f + e2), -1.0f);  // tanh(c)
        float hn = a3 * th;                        // h = o * tanh(c)
#pragma unroll
        for (int k = 0; k < Hs; ++k)
            hs[k] = __int_as_float(__builtin_amdgcn_readlane(__float_as_int(hn), 4 * k));
        gcur = gn; gp = gpn;
    }
    if (lane == 0) {
        float o = lin_b[0];
#pragma unroll
        for (int k = 0; k < Hs; ++k) o = fmaf(hs[k], lin_w[k], o);
        out[b0 + bl] = o;
    }
}

extern "C" void kernel_launch(void* const* d_in, const int* in_sizes, int n_in,
                              void* d_out, int out_size, void* d_ws, size_t ws_size,
                              hipStream_t stream) {
    const float* x = (const float*)d_in[0];
    float* w   = (float*)d_ws;
    float* out = (float*)d_out;

    prep_kernel<<<15, 256, 0, stream>>>(
        (const float*)d_in[1], (const float*)d_in[2], (const float*)d_in[3],
        (const float*)d_in[4], (const float*)d_in[5], (const float*)d_in[6],
        (const float*)d_in[7], (const float*)d_in[8], (const float*)d_in[9], w);

    // b-chunk so xg (bc*T*G floats) fits in ws; bc must be a multiple of 8
    // (so bc*T is a multiple of 64 rows per projection wave).
    long avail = (long)(ws_size / 4);
    long per_b = (long)Tlen * Gs;                 // 8000 floats per batch row
    long bcL = (avail - 4096 - 64) / per_b;
    int bc = (bcL >= Bsz) ? Bsz : (int)(bcL - (bcL % 8));
    if (bc < 8) bc = 8;
    float* xg = w + 4096;

    for (int b0 = 0; b0 < Bsz; b0 += bc) {
        int cur = (Bsz - b0 < bc) ? (Bsz - b0) : bc;
        long groups = (long)cur * Tlen / 64;      // 64-row wave groups
        int pblocks = (int)((groups + 1) / 2);    // 2 waves per block
        proj_kernel<<<pblocks, 128, 0, stream>>>(x, w, xg, b0, cur);
        rec_kernel<<<(cur + 3) / 4, 256, 0, stream>>>(
            xg, w, (const float*)d_in[10], (const float*)d_in[11], out, b0, cur);
    }
}